// Round 1
// baseline (367.846 us; speedup 1.0000x reference)
//
#include <hip/hip_runtime.h>
#include <math.h>

#define D_MODEL 1024
#define NWAVES  16
#define BLOCK_T (NWAVES * 64)

// One block per batch row b. 16 waves split the K dimension; each wave keeps a
// private online-softmax state (m, l, o[D]) with its lane holding 16 elements
// of o (d = j*256 + lane*4, j=0..3 -> coalesced float4 segments). Single pass
// over concept: each row is loaded once (register double-buffered) and used
// for both the score dot-product and the weighted accumulation.
__global__ __launch_bounds__(BLOCK_T, 1)
void denoise_attn_kernel(const float* __restrict__ q,
                         const float* __restrict__ c,
                         float* __restrict__ out, int K) {
    // 64 KiB: phase 1 aliases m[16], l[16] into the front; phase 2 holds the
    // 16 per-wave scaled o vectors for the cross-wave sum.
    __shared__ float smem[NWAVES * D_MODEL];

    const int b    = blockIdx.x;
    const int tid  = threadIdx.x;
    const int wave = tid >> 6;
    const int lane = tid & 63;

    const float scale = 0.03125f; // 1/sqrt(1024)
    const float* qrow  = q + (size_t)b * D_MODEL;
    const float* cbase = c + (size_t)b * (size_t)K * D_MODEL;

    // Resident query fragment: 16 floats/lane.
    float4 qf[4];
    #pragma unroll
    for (int j = 0; j < 4; ++j)
        qf[j] = *(const float4*)(qrow + j * 256 + lane * 4);

    float m = -INFINITY;
    float l = 0.f;
    float4 o[4];
    #pragma unroll
    for (int j = 0; j < 4; ++j) o[j] = make_float4(0.f, 0.f, 0.f, 0.f);

    // Prefetch first row for this wave.
    float4 nxt[4];
    {
        const float* crow = cbase + (size_t)wave * D_MODEL;
        #pragma unroll
        for (int j = 0; j < 4; ++j)
            nxt[j] = *(const float4*)(crow + j * 256 + lane * 4);
    }

    for (int k = wave; k < K; k += NWAVES) {
        float4 cur[4];
        #pragma unroll
        for (int j = 0; j < 4; ++j) cur[j] = nxt[j];

        const int kn = k + NWAVES;
        if (kn < K) { // wave-uniform branch
            const float* crn = cbase + (size_t)kn * D_MODEL;
            #pragma unroll
            for (int j = 0; j < 4; ++j)
                nxt[j] = *(const float4*)(crn + j * 256 + lane * 4);
        }

        // Per-lane partial dot (16 FMA), then 64-lane butterfly reduce.
        float s = 0.f;
        #pragma unroll
        for (int j = 0; j < 4; ++j) {
            s = fmaf(cur[j].x, qf[j].x, s);
            s = fmaf(cur[j].y, qf[j].y, s);
            s = fmaf(cur[j].z, qf[j].z, s);
            s = fmaf(cur[j].w, qf[j].w, s);
        }
        #pragma unroll
        for (int off = 32; off >= 1; off >>= 1)
            s += __shfl_xor(s, off, 64);
        s *= scale;

        // Online softmax update (first iter: m=-inf -> corr=exp(-inf)=0).
        const float mn   = fmaxf(m, s);
        const float corr = __expf(m - mn);
        const float p    = __expf(s - mn);
        l = l * corr + p;
        #pragma unroll
        for (int j = 0; j < 4; ++j) {
            o[j].x = fmaf(o[j].x, corr, p * cur[j].x);
            o[j].y = fmaf(o[j].y, corr, p * cur[j].y);
            o[j].z = fmaf(o[j].z, corr, p * cur[j].z);
            o[j].w = fmaf(o[j].w, corr, p * cur[j].w);
        }
        m = mn;
    }

    // ---- Cross-wave combine ----
    // Phase 1: publish per-wave (m, l) in the front of smem.
    if (lane == 0) {
        smem[wave]          = m;
        smem[NWAVES + wave] = l;
    }
    __syncthreads();

    float M = -INFINITY;
    #pragma unroll
    for (int w = 0; w < NWAVES; ++w) M = fmaxf(M, smem[w]);
    float L = 0.f;
    #pragma unroll
    for (int w = 0; w < NWAVES; ++w) L += smem[NWAVES + w] * __expf(smem[w] - M);

    const float wscale = __expf(m - M) / L; // wave-uniform
    __syncthreads(); // all reads of m/l done before o overwrites smem

    // Phase 2: each wave writes its scaled o vector.
    #pragma unroll
    for (int j = 0; j < 4; ++j) {
        float4 t;
        t.x = o[j].x * wscale;
        t.y = o[j].y * wscale;
        t.z = o[j].z * wscale;
        t.w = o[j].w * wscale;
        *(float4*)&smem[wave * D_MODEL + j * 256 + lane * 4] = t;
    }
    __syncthreads();

    // Phase 3: thread tid sums column tid across the 16 wave vectors.
    float acc = 0.f;
    #pragma unroll
    for (int w = 0; w < NWAVES; ++w) acc += smem[w * D_MODEL + tid];
    out[(size_t)b * D_MODEL + tid] = acc;
}

extern "C" void kernel_launch(void* const* d_in, const int* in_sizes, int n_in,
                              void* d_out, int out_size, void* d_ws, size_t ws_size,
                              hipStream_t stream) {
    const float* q = (const float*)d_in[0];
    const float* c = (const float*)d_in[1];
    float* out     = (float*)d_out;

    const int BD = in_sizes[0];          // B * D
    const int B  = BD / D_MODEL;         // 256
    const int K  = in_sizes[1] / BD;     // 2048

    denoise_attn_kernel<<<dim3(B), dim3(BLOCK_T), 0, stream>>>(q, c, out, K);
}

// Round 3
// 324.958 us; speedup vs baseline: 1.1320x; 1.1320x over previous
//
#include <hip/hip_runtime.h>
#include <math.h>

#define D_MODEL 1024
#define NWAVES  16
#define BLOCK_T (NWAVES * 64)

typedef float f32x4 __attribute__((ext_vector_type(4)));

// One block per batch row b. 16 waves split the K dimension; each wave keeps a
// private online-softmax state (m, l, o[D]) with its lane holding 16 elements
// of o (d = j*256 + lane*4 -> coalesced float4 segments). Single pass over
// concept: each row loaded exactly once (A/B register double-buffer, no copy)
// and used for both the score dot and the weighted accumulation.
// Non-temporal loads: concept is read-once, skip cache retention.
__global__ __launch_bounds__(BLOCK_T, 4) // 4 waves/EU -> VGPR cap 128
void denoise_attn_kernel(const float* __restrict__ q,
                         const float* __restrict__ c,
                         float* __restrict__ out, int K) {
    __shared__ float smem[NWAVES * D_MODEL]; // 64 KiB, reused across phases

    const int tid  = threadIdx.x;
    const int wave = tid >> 6;
    const int lane = tid & 63;

    const float scale = 0.03125f; // 1/sqrt(1024)
    const float* qrow  = q + (size_t)blockIdx.x * D_MODEL;
    const float* cbase = c + (size_t)blockIdx.x * (size_t)K * D_MODEL;
    const int laneoff  = lane * 4;

    f32x4 qf[4];
    #pragma unroll
    for (int j = 0; j < 4; ++j)
        qf[j] = *(const f32x4*)(qrow + j * 256 + laneoff);

    float m = -INFINITY;
    float l = 0.f;
    f32x4 o[4];
    #pragma unroll
    for (int j = 0; j < 4; ++j) o[j] = (f32x4)(0.f);

    f32x4 bufA[4], bufB[4];

    auto loadrow = [&](f32x4* buf, int k) {
        const float* crow = cbase + (size_t)k * D_MODEL + laneoff;
        #pragma unroll
        for (int j = 0; j < 4; ++j)
            buf[j] = __builtin_nontemporal_load((const f32x4*)(crow + j * 256));
    };

    // dot + online-softmax + weighted accumulate for one resident row.
    auto process = [&](const f32x4* cur) {
        float s0 = 0.f, s1 = 0.f, s2 = 0.f, s3 = 0.f;
        #pragma unroll
        for (int e = 0; e < 4; ++e) {
            s0 = fmaf(cur[0][e], qf[0][e], s0);
            s1 = fmaf(cur[1][e], qf[1][e], s1);
            s2 = fmaf(cur[2][e], qf[2][e], s2);
            s3 = fmaf(cur[3][e], qf[3][e], s3);
        }
        float s = (s0 + s1) + (s2 + s3);
        #pragma unroll
        for (int off = 32; off >= 1; off >>= 1)
            s += __shfl_xor(s, off, 64);
        s *= scale;

        const float mn   = fmaxf(m, s);
        const float corr = __expf(m - mn);
        const float p    = __expf(s - mn);
        l = l * corr + p;
        #pragma unroll
        for (int j = 0; j < 4; ++j) {
            #pragma unroll
            for (int e = 0; e < 4; ++e)
                o[j][e] = fmaf(o[j][e], corr, p * cur[j][e]);
        }
        m = mn;
    };

    int kA = wave;           // rows wave, wave+32, ...
    int kB = wave + NWAVES;  // rows wave+16, wave+48, ...
    bool hasA = kA < K, hasB = kB < K;
    if (hasA) loadrow(bufA, kA);
    if (hasB) loadrow(bufB, kB);

    while (hasA) { // wave-uniform trip count (K % 16 == 0 in practice)
        process(bufA);
        kA += 2 * NWAVES;
        hasA = kA < K;
        if (hasA) loadrow(bufA, kA);

        if (hasB) {
            process(bufB);
            kB += 2 * NWAVES;
            hasB = kB < K;
            if (hasB) loadrow(bufB, kB);
        }
    }

    // ---- Cross-wave combine ----
    if (lane == 0) {
        smem[wave]          = m;
        smem[NWAVES + wave] = l;
    }
    __syncthreads();

    float M = -INFINITY;
    #pragma unroll
    for (int w = 0; w < NWAVES; ++w) M = fmaxf(M, smem[w]);
    float L = 0.f;
    #pragma unroll
    for (int w = 0; w < NWAVES; ++w) L += smem[NWAVES + w] * __expf(smem[w] - M);

    const float wscale = __expf(m - M) / L; // wave-uniform
    __syncthreads(); // m/l reads done before o overwrites smem

    #pragma unroll
    for (int j = 0; j < 4; ++j) {
        f32x4 t = o[j] * wscale;
        *(f32x4*)&smem[wave * D_MODEL + j * 256 + laneoff] = t;
    }
    __syncthreads();

    float acc = 0.f;
    #pragma unroll
    for (int w = 0; w < NWAVES; ++w) acc += smem[w * D_MODEL + tid];
    out[(size_t)blockIdx.x * D_MODEL + tid] = acc;
}

extern "C" void kernel_launch(void* const* d_in, const int* in_sizes, int n_in,
                              void* d_out, int out_size, void* d_ws, size_t ws_size,
                              hipStream_t stream) {
    const float* q = (const float*)d_in[0];
    const float* c = (const float*)d_in[1];
    float* out     = (float*)d_out;

    const int BD = in_sizes[0];          // B * D
    const int B  = BD / D_MODEL;         // 256
    const int K  = in_sizes[1] / BD;     // 2048

    denoise_attn_kernel<<<dim3(B), dim3(BLOCK_T), 0, stream>>>(q, c, out, K);
}